// Round 6
// baseline (621.870 us; speedup 1.0000x reference)
//
#include <hip/hip_runtime.h>

#define N_NODES 50000
#define N_EDGES 600000
#define DIM 128
#define N_GRAPHS 512
#define N_LAYERS 3
#define OUT_STRIDE (N_LAYERS * DIM)
#define BN_EPS 1e-5f
#define N_CHUNKS 49  // ceil(50000/1024)

typedef __attribute__((ext_vector_type(8))) short short8;
typedef __attribute__((ext_vector_type(4))) float floatx4;

__device__ inline short f2bf(float f) {
    union { float f; unsigned u; } x{f};
    unsigned r = x.u + 0x7fffu + ((x.u >> 16) & 1u);
    return (short)(r >> 16);
}
__device__ inline float bf2f(short h) {
    union { unsigned u; float f; } x;
    x.u = ((unsigned)(unsigned short)h) << 16;
    return x.f;
}
// exact truncation split: f == bf2f(hi) + bf2f(lo) + O(2^-16 |f|)
__device__ inline void split_trunc(float f, short& hi, short& lo) {
    union { float f; unsigned u; } x{f};
    hi = (short)(x.u >> 16);
    union { unsigned u; float f; } hf;
    hf.u = x.u & 0xffff0000u;
    union { float f; unsigned u; } y{f - hf.f};
    lo = (short)(y.u >> 16);
}

// ---------------- CSR build (+ per-graph node count) ----------------
__global__ __launch_bounds__(256) void degree_count_kernel(const int* __restrict__ dst,
                                                           const int* __restrict__ batch,
                                                           int* __restrict__ deg,
                                                           int* __restrict__ cnt) {
    int i = blockIdx.x * 256 + threadIdx.x;
    if (i < N_EDGES) atomicAdd(&deg[dst[i]], 1);
    if (i < N_NODES) atomicAdd(&cnt[batch[i]], 1);
}

__global__ __launch_bounds__(1024) void scan1_kernel(const int* __restrict__ deg,
                                                     int* __restrict__ ptr,
                                                     int* __restrict__ partials) {
    __shared__ int buf[1024];
    int i = blockIdx.x * 1024 + threadIdx.x;
    int v = (i < N_NODES) ? deg[i] : 0;
    buf[threadIdx.x] = v;
    __syncthreads();
    for (int off = 1; off < 1024; off <<= 1) {
        int t = (threadIdx.x >= (unsigned)off) ? buf[threadIdx.x - off] : 0;
        __syncthreads();
        buf[threadIdx.x] += t;
        __syncthreads();
    }
    if (i < N_NODES) ptr[i] = buf[threadIdx.x] - v;  // chunk-local exclusive
    if (threadIdx.x == 1023) partials[blockIdx.x] = buf[1023];
}

__global__ __launch_bounds__(64) void scan2_kernel(int* __restrict__ partials) {
    if (threadIdx.x == 0) {
        int run = 0;
        for (int i = 0; i < N_CHUNKS; ++i) { int t = partials[i]; partials[i] = run; run += t; }
    }
}

__global__ __launch_bounds__(256) void scan3_kernel(const int* __restrict__ partials,
                                                    int* __restrict__ ptr,
                                                    int* __restrict__ cursor) {
    int i = blockIdx.x * 256 + threadIdx.x;
    if (i < N_NODES) {
        int p = ptr[i] + partials[i >> 10];
        ptr[i] = p;
        cursor[i] = p;
    }
    if (i == N_NODES) ptr[N_NODES] = N_EDGES;
}

__global__ __launch_bounds__(256) void fill_kernel(const int* __restrict__ src,
                                                   const int* __restrict__ dst,
                                                   int* __restrict__ cursor,
                                                   int* __restrict__ esrc) {
    int e = blockIdx.x * 256 + threadIdx.x;
    if (e < N_EDGES) {
        int slot = atomicAdd(&cursor[dst[e]], 1);
        esrc[slot] = src[e];
    }
}

// ---------------- weight convert: W[k][n] -> Wt_hi/lo[mat][n][k] (split bf16) ----------------
__global__ __launch_bounds__(256) void wconv_kernel(const float* __restrict__ W1s,
                                                    const float* __restrict__ W2s,
                                                    short* __restrict__ Whi,
                                                    short* __restrict__ Wlo) {
    int idx = blockIdx.x * 256 + threadIdx.x;
    if (idx >= 6 * DIM * DIM) return;
    int mat = idx >> 14;
    int e = idx & 16383;
    int k = e >> 7, n = e & 127;
    const float* W = (mat < 3) ? (W1s + (size_t)mat * DIM * DIM)
                               : (W2s + (size_t)(mat - 3) * DIM * DIM);
    float w = W[e];
    short hi = f2bf(w);
    short lo = f2bf(w - bf2f(hi));
    size_t o = ((size_t)mat << 14) + n * DIM + k;
    Whi[o] = hi;
    Wlo[o] = lo;
}

// ---- gather + inline prev-layer BN affine: agg[n] = G*(h2[n]+sum h2[j]) + (deg+1)*OFF ----
__global__ __launch_bounds__(256) void gather_kernel(const float* __restrict__ hin,
                                                     const int* __restrict__ ptr,
                                                     const int* __restrict__ esrc,
                                                     const float* __restrict__ stats,  // null=>id
                                                     const float* __restrict__ gamma,
                                                     const float* __restrict__ beta,
                                                     float* __restrict__ agg) {
    int node = (blockIdx.x * 256 + threadIdx.x) >> 6;
    int lane = threadIdx.x & 63;
    if (node >= N_NODES) return;
    float Gx = 1.f, Gy = 1.f, Ox = 0.f, Oy = 0.f;
    if (stats) {
        int c0 = lane * 2;
        const float invn = 1.0f / (float)N_NODES;
        float m0 = stats[c0] * invn, m1 = stats[c0 + 1] * invn;
        float v0 = stats[128 + c0] * invn - m0 * m0;
        float v1 = stats[128 + c0 + 1] * invn - m1 * m1;
        float i0 = rsqrtf(v0 + BN_EPS), i1 = rsqrtf(v1 + BN_EPS);
        Gx = gamma[c0] * i0;
        Gy = gamma[c0 + 1] * i1;
        Ox = beta[c0] - m0 * Gx;
        Oy = beta[c0 + 1] - m1 * Gy;
    }
    const float2* h2p = (const float2*)hin;
    float2 acc = h2p[(size_t)node * 64 + lane];  // self term (eps=0)
    int b = ptr[node], e = ptr[node + 1];
    int j = b;
    // unroll by 8: 8 independent 512B row loads in flight (latency-bound loop)
    for (; j + 8 <= e; j += 8) {
        int s0 = esrc[j], s1 = esrc[j + 1], s2 = esrc[j + 2], s3 = esrc[j + 3];
        int s4 = esrc[j + 4], s5 = esrc[j + 5], s6 = esrc[j + 6], s7 = esrc[j + 7];
        float2 v0 = h2p[(size_t)s0 * 64 + lane];
        float2 v1 = h2p[(size_t)s1 * 64 + lane];
        float2 v2 = h2p[(size_t)s2 * 64 + lane];
        float2 v3 = h2p[(size_t)s3 * 64 + lane];
        float2 v4 = h2p[(size_t)s4 * 64 + lane];
        float2 v5 = h2p[(size_t)s5 * 64 + lane];
        float2 v6 = h2p[(size_t)s6 * 64 + lane];
        float2 v7 = h2p[(size_t)s7 * 64 + lane];
        acc.x += ((v0.x + v1.x) + (v2.x + v3.x)) + ((v4.x + v5.x) + (v6.x + v7.x));
        acc.y += ((v0.y + v1.y) + (v2.y + v3.y)) + ((v4.y + v5.y) + (v6.y + v7.y));
    }
    if (j + 4 <= e) {
        int s0 = esrc[j], s1 = esrc[j + 1], s2 = esrc[j + 2], s3 = esrc[j + 3];
        float2 v0 = h2p[(size_t)s0 * 64 + lane];
        float2 v1 = h2p[(size_t)s1 * 64 + lane];
        float2 v2 = h2p[(size_t)s2 * 64 + lane];
        float2 v3 = h2p[(size_t)s3 * 64 + lane];
        acc.x += (v0.x + v1.x) + (v2.x + v3.x);
        acc.y += (v0.y + v1.y) + (v2.y + v3.y);
        j += 4;
    }
    for (; j < e; ++j) {
        int s = esrc[j];
        float2 v = h2p[(size_t)s * 64 + lane];
        acc.x += v.x;
        acc.y += v.y;
    }
    float dp1 = (float)(e - b + 1);
    float2 r;
    r.x = fmaf(Gx, acc.x, dp1 * Ox);
    r.y = fmaf(Gy, acc.y, dp1 * Oy);
    ((float2*)agg)[(size_t)node * 64 + lane] = r;
}

// -------- fused MLP + BN-stats + raw segmented pool: split-bf16 MFMA --------
// 128-row block, 4 waves; wave = 32 rows x 128 cols (2x8 MFMA tiles of 16x16x32).
// A hi/lo staged in LDS (XOR swizzle); h1 round-trips through same LDS as packed (hi|lo) u32.
// Epilogue: writes raw h2, accumulates per-feature sum/sumsq (LDS->global atomics) and
// per-graph raw pool (4-slot LDS buffer; batch sorted => <=3 graphs per 128-row window).
__global__ __launch_bounds__(256) void mlp_kernel(const float* __restrict__ in,
                                                  const short* __restrict__ W1hi,
                                                  const short* __restrict__ W1lo,
                                                  const float* __restrict__ b1,
                                                  const short* __restrict__ W2hi,
                                                  const short* __restrict__ W2lo,
                                                  const float* __restrict__ b2,
                                                  const int* __restrict__ batch,
                                                  float* __restrict__ out,     // raw h2 [N,128]
                                                  float* __restrict__ stats,   // [256]
                                                  float* __restrict__ gout,    // [G, 384]
                                                  int layer) {
    __shared__ unsigned sbuf[16384];  // 64 KB, aliased across phases
    short* As_hi = (short*)sbuf;      // [128][128] shorts, chunk^row swizzle
    short* As_lo = (short*)(sbuf + 8192);
    const int tid = threadIdx.x;
    const int base = blockIdx.x * 128;

    // phase 0: stage A (fp32 -> hi/lo trunc split)
    const float4* asrc = (const float4*)in;
#pragma unroll
    for (int it = 0; it < 8; ++it) {
        int c = tid + it * 256;  // 0..2047
        int r = c >> 4, ch = c & 15;
        int row = base + r;
        float4 v0 = make_float4(0.f, 0.f, 0.f, 0.f), v1 = v0;
        if (row < N_NODES) {
            v0 = asrc[(size_t)row * 32 + ch * 2];
            v1 = asrc[(size_t)row * 32 + ch * 2 + 1];
        }
        float f[8] = {v0.x, v0.y, v0.z, v0.w, v1.x, v1.y, v1.z, v1.w};
        short8 hi, lo;
#pragma unroll
        for (int j = 0; j < 8; ++j) {
            short h, l;
            split_trunc(f[j], h, l);
            hi[j] = h;
            lo[j] = l;
        }
        int pos = r * 128 + ((ch ^ (r & 15)) * 8);
        *(short8*)&As_hi[pos] = hi;
        *(short8*)&As_lo[pos] = lo;
    }
    __syncthreads();

    const int wave = tid >> 6;
    const int lane = tid & 63;
    const int wm = wave * 32;
    const int l15 = lane & 15;
    const int quad = lane >> 4;

    // phase 1: preload all A fragments, then GEMM1
    short8 Ahi[4][2], Alo[4][2];
#pragma unroll
    for (int ks = 0; ks < 4; ++ks)
#pragma unroll
        for (int mi = 0; mi < 2; ++mi) {
            int row = wm + mi * 16 + l15;
            int pos = row * 128 + (((ks * 4 + quad) ^ l15) * 8);
            Ahi[ks][mi] = *(const short8*)&As_hi[pos];
            Alo[ks][mi] = *(const short8*)&As_lo[pos];
        }
    floatx4 acc[2][8];
#pragma unroll
    for (int mi = 0; mi < 2; ++mi)
#pragma unroll
        for (int ni = 0; ni < 8; ++ni) acc[mi][ni] = floatx4{0.f, 0.f, 0.f, 0.f};
#pragma unroll
    for (int ks = 0; ks < 4; ++ks) {
#pragma unroll
        for (int ni = 0; ni < 8; ++ni) {
            size_t p = (size_t)(ni * 16 + l15) * DIM + ks * 32 + quad * 8;
            short8 bhi = *(const short8*)&W1hi[p];
            short8 blo = *(const short8*)&W1lo[p];
#pragma unroll
            for (int mi = 0; mi < 2; ++mi) {
                acc[mi][ni] = __builtin_amdgcn_mfma_f32_16x16x32_bf16(Ahi[ks][mi], bhi, acc[mi][ni], 0, 0, 0);
                acc[mi][ni] = __builtin_amdgcn_mfma_f32_16x16x32_bf16(Alo[ks][mi], bhi, acc[mi][ni], 0, 0, 0);
                acc[mi][ni] = __builtin_amdgcn_mfma_f32_16x16x32_bf16(Ahi[ks][mi], blo, acc[mi][ni], 0, 0, 0);
            }
        }
    }
    __syncthreads();  // all As reads complete before overwrite

    // phase 2: bias1 + relu, trunc-split, pack (hi<<16|lo) -> LDS u32, 16B-chunk swizzle
#pragma unroll
    for (int mi = 0; mi < 2; ++mi)
#pragma unroll
        for (int ni = 0; ni < 8; ++ni) {
            float bv = b1[ni * 16 + l15];
            int col = ni * 16 + l15;
#pragma unroll
            for (int reg = 0; reg < 4; ++reg) {
                int row = wm + mi * 16 + quad * 4 + reg;
                float v = fmaxf(acc[mi][ni][reg] + bv, 0.f);
                union { float f; unsigned u; } x{v};
                union { unsigned u; float f; } hf;
                hf.u = x.u & 0xffff0000u;
                union { float f; unsigned u; } y{v - hf.f};
                unsigned w = hf.u | (y.u >> 16);
                sbuf[row * 128 + ((((col >> 2) ^ (row & 31)) * 4) + (col & 3))] = w;
            }
        }
    __syncthreads();

    // phase 3: GEMM2 from packed h1
    floatx4 acc2[2][8];
#pragma unroll
    for (int mi = 0; mi < 2; ++mi)
#pragma unroll
        for (int ni = 0; ni < 8; ++ni) acc2[mi][ni] = floatx4{0.f, 0.f, 0.f, 0.f};
#pragma unroll
    for (int ks = 0; ks < 4; ++ks) {
        short8 ahi2[2], alo2[2];
#pragma unroll
        for (int mi = 0; mi < 2; ++mi) {
            int row = wm + mi * 16 + l15;
            int c5 = ks * 8 + quad * 2;
            unsigned w[8];
            *(uint4*)&w[0] = *(const uint4*)&sbuf[row * 128 + ((c5 ^ (row & 31)) * 4)];
            *(uint4*)&w[4] = *(const uint4*)&sbuf[row * 128 + (((c5 + 1) ^ (row & 31)) * 4)];
#pragma unroll
            for (int j = 0; j < 8; ++j) {
                ahi2[mi][j] = (short)(w[j] >> 16);
                alo2[mi][j] = (short)(w[j] & 0xffffu);
            }
        }
#pragma unroll
        for (int ni = 0; ni < 8; ++ni) {
            size_t p = (size_t)(ni * 16 + l15) * DIM + ks * 32 + quad * 8;
            short8 bhi = *(const short8*)&W2hi[p];
            short8 blo = *(const short8*)&W2lo[p];
#pragma unroll
            for (int mi = 0; mi < 2; ++mi) {
                acc2[mi][ni] = __builtin_amdgcn_mfma_f32_16x16x32_bf16(ahi2[mi], bhi, acc2[mi][ni], 0, 0, 0);
                acc2[mi][ni] = __builtin_amdgcn_mfma_f32_16x16x32_bf16(alo2[mi], bhi, acc2[mi][ni], 0, 0, 0);
                acc2[mi][ni] = __builtin_amdgcn_mfma_f32_16x16x32_bf16(ahi2[mi], blo, acc2[mi][ni], 0, 0, 0);
            }
        }
    }
    __syncthreads();  // phase-3 sbuf reads done; reuse LDS for pool/stats

    // phase 4: epilogue — h2 store + fused stats + segmented pool
    float* pool_s = (float*)sbuf;        // [4][128]
    float* sum_s = (float*)sbuf + 512;   // [128]
    float* sq_s = (float*)sbuf + 640;    // [128]
    for (int i = tid; i < 768; i += 256) ((float*)sbuf)[i] = 0.f;
    __syncthreads();

    const int g0 = batch[base];
    int idxr[2][4];
#pragma unroll
    for (int mi = 0; mi < 2; ++mi)
#pragma unroll
        for (int reg = 0; reg < 4; ++reg) {
            int row = base + wm + mi * 16 + quad * 4 + reg;
            idxr[mi][reg] = (row < N_NODES) ? (batch[row] - g0) : -1;
        }

#pragma unroll
    for (int mi = 0; mi < 2; ++mi)
#pragma unroll
        for (int ni = 0; ni < 8; ++ni) {
            float bv = b2[ni * 16 + l15];
            int col = ni * 16 + l15;
            float s_p = 0.f, q_p = 0.f;
#pragma unroll
            for (int reg = 0; reg < 4; ++reg) {
                int row = base + wm + mi * 16 + quad * 4 + reg;
                int idx = idxr[mi][reg];
                if (idx >= 0) {
                    float v = fmaxf(acc2[mi][ni][reg] + bv, 0.f);
                    out[(size_t)row * DIM + col] = v;
                    s_p += v;
                    q_p += v * v;
                    if (idx < 4)
                        atomicAdd(&pool_s[idx * 128 + col], v);
                    else
                        atomicAdd(&gout[(size_t)(g0 + idx) * OUT_STRIDE + layer * DIM + col], v);
                }
            }
            atomicAdd(&sum_s[col], s_p);
            atomicAdd(&sq_s[col], q_p);
        }
    __syncthreads();

    if (tid < 128)
        atomicAdd(&stats[tid], sum_s[tid]);
    else
        atomicAdd(&stats[tid], sq_s[tid - 128]);  // stats[128+c]
    for (int i = tid; i < 512; i += 256) {
        float pv = pool_s[i];
        if (pv != 0.f) {
            int g = g0 + (i >> 7);
            if (g < N_GRAPHS)
                atomicAdd(&gout[(size_t)g * OUT_STRIDE + layer * DIM + (i & 127)], pv);
        }
    }
}

// ------- finalize: out[b, l*128+c] = G_l[c]*rawpool + cnt[b]*OFF_l[c] -------
__global__ __launch_bounds__(384) void finalize_kernel(const float* __restrict__ stats3,
                                                       const float* __restrict__ gammas,
                                                       const float* __restrict__ betas,
                                                       const int* __restrict__ cnt,
                                                       float* __restrict__ out) {
    int b = blockIdx.x;
    int l = threadIdx.x >> 7, c = threadIdx.x & 127;
    const float invn = 1.0f / (float)N_NODES;
    const float* st = stats3 + l * 256;
    float m = st[c] * invn;
    float var = st[128 + c] * invn - m * m;
    float inv = rsqrtf(var + BN_EPS);
    float G = gammas[l * DIM + c] * inv;
    float OFF = betas[l * DIM + c] - m * G;
    size_t o = (size_t)b * OUT_STRIDE + threadIdx.x;
    out[o] = fmaf(G, out[o], (float)cnt[b] * OFF);
}

extern "C" void kernel_launch(void* const* d_in, const int* in_sizes, int n_in,
                              void* d_out, int out_size, void* d_ws, size_t ws_size,
                              hipStream_t stream) {
    const float* x = (const float*)d_in[0];
    const int* ei = (const int*)d_in[1];
    const int* srcp = ei;
    const int* dstp = ei + N_EDGES;
    const int* batch = (const int*)d_in[2];
    const float* W1s = (const float*)d_in[3];
    const float* b1s = (const float*)d_in[4];
    const float* W2s = (const float*)d_in[5];
    const float* b2s = (const float*)d_in[6];
    const float* gammas = (const float*)d_in[7];
    const float* betas = (const float*)d_in[8];
    float* out = (float*)d_out;

    float* ws = (float*)d_ws;
    const size_t NF = (size_t)N_NODES * DIM;  // 6.4M floats
    float* hbuf = ws;                         // fp32 [N,128] raw h2 of current layer
    float* agg = ws + NF;                     // fp32 [N,128]
    short* whi = (short*)(ws + 2 * NF);       // bf16 hi [6][128][128]
    short* wlo = whi + 6 * DIM * DIM;         // bf16 lo [6][128][128] (together 98304 floats)
    float* stats3 = ws + 2 * NF + 98304;      // 3*256 floats
    int* cnt = (int*)(stats3 + 3 * 256);      // 512
    int* deg = cnt + N_GRAPHS;                // 50000
    int* ptr = deg + N_NODES;                 // 50001
    int* cursor = ptr + N_NODES + 1;          // 50000
    int* esrc = cursor + N_NODES;             // 600000
    int* partials = esrc + N_EDGES;           // 64

    hipMemsetAsync(out, 0, (size_t)N_GRAPHS * OUT_STRIDE * sizeof(float), stream);
    hipMemsetAsync(stats3, 0, (3 * 256) * sizeof(float) + (N_GRAPHS + N_NODES) * sizeof(int),
                   stream);

    // CSR build (once; reused by all layers) + per-graph node counts
    degree_count_kernel<<<(N_EDGES + 255) / 256, 256, 0, stream>>>(dstp, batch, deg, cnt);
    scan1_kernel<<<N_CHUNKS, 1024, 0, stream>>>(deg, ptr, partials);
    scan2_kernel<<<1, 64, 0, stream>>>(partials);
    scan3_kernel<<<(N_NODES + 256) / 256, 256, 0, stream>>>(partials, ptr, cursor);
    fill_kernel<<<(N_EDGES + 255) / 256, 256, 0, stream>>>(srcp, dstp, cursor, esrc);
    wconv_kernel<<<(6 * DIM * DIM + 255) / 256, 256, 0, stream>>>(W1s, W2s, whi, wlo);

    const int nblk = (N_NODES + 127) / 128;  // 391
    for (int layer = 0; layer < N_LAYERS; ++layer) {
        const float* hin = (layer == 0) ? x : hbuf;
        const float* stp = (layer == 0) ? nullptr : (stats3 + (layer - 1) * 256);
        const float* gp = gammas + (layer - 1) * DIM;  // unused when stp==null
        const float* bp = betas + (layer - 1) * DIM;
        gather_kernel<<<(N_NODES * 64 + 255) / 256, 256, 0, stream>>>(hin, ptr, esrc, stp, gp, bp,
                                                                      agg);
        mlp_kernel<<<nblk, 256, 0, stream>>>(
            agg, whi + ((size_t)layer << 14), wlo + ((size_t)layer << 14), b1s + layer * DIM,
            whi + ((size_t)(3 + layer) << 14), wlo + ((size_t)(3 + layer) << 14),
            b2s + layer * DIM, batch, hbuf, stats3 + layer * 256, out, layer);
    }
    finalize_kernel<<<N_GRAPHS, 384, 0, stream>>>(stats3, gammas, betas, cnt, out);
}

// Round 7
// 549.293 us; speedup vs baseline: 1.1321x; 1.1321x over previous
//
#include <hip/hip_runtime.h>

#define N_NODES 50000
#define N_EDGES 600000
#define DIM 128
#define N_GRAPHS 512
#define N_LAYERS 3
#define OUT_STRIDE (N_LAYERS * DIM)
#define BN_EPS 1e-5f
#define N_CHUNKS 49  // ceil(50000/1024)

typedef __attribute__((ext_vector_type(8))) short short8;
typedef __attribute__((ext_vector_type(4))) float floatx4;

__device__ inline short f2bf(float f) {
    union { float f; unsigned u; } x{f};
    unsigned r = x.u + 0x7fffu + ((x.u >> 16) & 1u);
    return (short)(r >> 16);
}
__device__ inline float bf2f(short h) {
    union { unsigned u; float f; } x;
    x.u = ((unsigned)(unsigned short)h) << 16;
    return x.f;
}
// exact truncation split: f == bf2f(hi) + bf2f(lo) + O(2^-16 |f|)
__device__ inline void split_trunc(float f, short& hi, short& lo) {
    union { float f; unsigned u; } x{f};
    hi = (short)(x.u >> 16);
    union { unsigned u; float f; } hf;
    hf.u = x.u & 0xffff0000u;
    union { float f; unsigned u; } y{f - hf.f};
    lo = (short)(y.u >> 16);
}

// ---------------- CSR build (+ per-graph node count) ----------------
__global__ __launch_bounds__(256) void degree_count_kernel(const int* __restrict__ dst,
                                                           const int* __restrict__ batch,
                                                           int* __restrict__ deg,
                                                           int* __restrict__ cnt) {
    int i = blockIdx.x * 256 + threadIdx.x;
    if (i < N_EDGES) atomicAdd(&deg[dst[i]], 1);
    if (i < N_NODES) atomicAdd(&cnt[batch[i]], 1);
}

__global__ __launch_bounds__(1024) void scan1_kernel(const int* __restrict__ deg,
                                                     int* __restrict__ ptr,
                                                     int* __restrict__ partials) {
    __shared__ int buf[1024];
    int i = blockIdx.x * 1024 + threadIdx.x;
    int v = (i < N_NODES) ? deg[i] : 0;
    buf[threadIdx.x] = v;
    __syncthreads();
    for (int off = 1; off < 1024; off <<= 1) {
        int t = (threadIdx.x >= (unsigned)off) ? buf[threadIdx.x - off] : 0;
        __syncthreads();
        buf[threadIdx.x] += t;
        __syncthreads();
    }
    if (i < N_NODES) ptr[i] = buf[threadIdx.x] - v;  // chunk-local exclusive
    if (threadIdx.x == 1023) partials[blockIdx.x] = buf[1023];
}

__global__ __launch_bounds__(64) void scan2_kernel(int* __restrict__ partials) {
    if (threadIdx.x == 0) {
        int run = 0;
        for (int i = 0; i < N_CHUNKS; ++i) { int t = partials[i]; partials[i] = run; run += t; }
    }
}

__global__ __launch_bounds__(256) void scan3_kernel(const int* __restrict__ partials,
                                                    int* __restrict__ ptr,
                                                    int* __restrict__ cursor) {
    int i = blockIdx.x * 256 + threadIdx.x;
    if (i < N_NODES) {
        int p = ptr[i] + partials[i >> 10];
        ptr[i] = p;
        cursor[i] = p;
    }
    if (i == N_NODES) ptr[N_NODES] = N_EDGES;
}

__global__ __launch_bounds__(256) void fill_kernel(const int* __restrict__ src,
                                                   const int* __restrict__ dst,
                                                   int* __restrict__ cursor,
                                                   int* __restrict__ esrc) {
    int e = blockIdx.x * 256 + threadIdx.x;
    if (e < N_EDGES) {
        int slot = atomicAdd(&cursor[dst[e]], 1);
        esrc[slot] = src[e];
    }
}

// ---------------- weight convert: W[k][n] -> Wt_hi/lo[mat][n][k] (split bf16) ----------------
__global__ __launch_bounds__(256) void wconv_kernel(const float* __restrict__ W1s,
                                                    const float* __restrict__ W2s,
                                                    short* __restrict__ Whi,
                                                    short* __restrict__ Wlo) {
    int idx = blockIdx.x * 256 + threadIdx.x;
    if (idx >= 6 * DIM * DIM) return;
    int mat = idx >> 14;
    int e = idx & 16383;
    int k = e >> 7, n = e & 127;
    const float* W = (mat < 3) ? (W1s + (size_t)mat * DIM * DIM)
                               : (W2s + (size_t)(mat - 3) * DIM * DIM);
    float w = W[e];
    short hi = f2bf(w);
    short lo = f2bf(w - bf2f(hi));
    size_t o = ((size_t)mat << 14) + n * DIM + k;
    Whi[o] = hi;
    Wlo[o] = lo;
}

// ---- gather + inline prev-layer BN affine: agg[n] = G*(h2[n]+sum h2[j]) + (deg+1)*OFF ----
__global__ __launch_bounds__(256) void gather_kernel(const float* __restrict__ hin,
                                                     const int* __restrict__ ptr,
                                                     const int* __restrict__ esrc,
                                                     const float* __restrict__ stats,  // null=>id
                                                     const float* __restrict__ gamma,
                                                     const float* __restrict__ beta,
                                                     float* __restrict__ agg) {
    int node = (blockIdx.x * 256 + threadIdx.x) >> 6;
    int lane = threadIdx.x & 63;
    if (node >= N_NODES) return;
    float Gx = 1.f, Gy = 1.f, Ox = 0.f, Oy = 0.f;
    if (stats) {
        int c0 = lane * 2;
        const float invn = 1.0f / (float)N_NODES;
        float m0 = stats[c0] * invn, m1 = stats[c0 + 1] * invn;
        float v0 = stats[128 + c0] * invn - m0 * m0;
        float v1 = stats[128 + c0 + 1] * invn - m1 * m1;
        float i0 = rsqrtf(v0 + BN_EPS), i1 = rsqrtf(v1 + BN_EPS);
        Gx = gamma[c0] * i0;
        Gy = gamma[c0 + 1] * i1;
        Ox = beta[c0] - m0 * Gx;
        Oy = beta[c0 + 1] - m1 * Gy;
    }
    const float2* h2p = (const float2*)hin;
    float2 acc = h2p[(size_t)node * 64 + lane];  // self term (eps=0)
    int b = ptr[node], e = ptr[node + 1];
    int j = b;
    for (; j + 8 <= e; j += 8) {
        int s0 = esrc[j], s1 = esrc[j + 1], s2 = esrc[j + 2], s3 = esrc[j + 3];
        int s4 = esrc[j + 4], s5 = esrc[j + 5], s6 = esrc[j + 6], s7 = esrc[j + 7];
        float2 v0 = h2p[(size_t)s0 * 64 + lane];
        float2 v1 = h2p[(size_t)s1 * 64 + lane];
        float2 v2 = h2p[(size_t)s2 * 64 + lane];
        float2 v3 = h2p[(size_t)s3 * 64 + lane];
        float2 v4 = h2p[(size_t)s4 * 64 + lane];
        float2 v5 = h2p[(size_t)s5 * 64 + lane];
        float2 v6 = h2p[(size_t)s6 * 64 + lane];
        float2 v7 = h2p[(size_t)s7 * 64 + lane];
        acc.x += ((v0.x + v1.x) + (v2.x + v3.x)) + ((v4.x + v5.x) + (v6.x + v7.x));
        acc.y += ((v0.y + v1.y) + (v2.y + v3.y)) + ((v4.y + v5.y) + (v6.y + v7.y));
    }
    if (j + 4 <= e) {
        int s0 = esrc[j], s1 = esrc[j + 1], s2 = esrc[j + 2], s3 = esrc[j + 3];
        float2 v0 = h2p[(size_t)s0 * 64 + lane];
        float2 v1 = h2p[(size_t)s1 * 64 + lane];
        float2 v2 = h2p[(size_t)s2 * 64 + lane];
        float2 v3 = h2p[(size_t)s3 * 64 + lane];
        acc.x += (v0.x + v1.x) + (v2.x + v3.x);
        acc.y += (v0.y + v1.y) + (v2.y + v3.y);
        j += 4;
    }
    for (; j < e; ++j) {
        int s = esrc[j];
        float2 v = h2p[(size_t)s * 64 + lane];
        acc.x += v.x;
        acc.y += v.y;
    }
    float dp1 = (float)(e - b + 1);
    float2 r;
    r.x = fmaf(Gx, acc.x, dp1 * Ox);
    r.y = fmaf(Gy, acc.y, dp1 * Oy);
    ((float2*)agg)[(size_t)node * 64 + lane] = r;
}

// -------- fused MLP + BN-stats + raw segmented pool: split-bf16 MFMA --------
// 64-row block (32 KB LDS -> 5 blocks/CU), 4 waves; wave = 16 rows x 128 cols (1x8 tiles).
// A hi/lo staged in LDS (XOR swizzle); h1 round-trips through same LDS as packed (hi|lo) u32.
// Epilogue: NO LDS atomics — quad-shfl reduction for stats, ownership-partitioned LDS for pool.
__global__ __launch_bounds__(256, 5) void mlp_kernel(const float* __restrict__ in,
                                                     const short* __restrict__ W1hi,
                                                     const short* __restrict__ W1lo,
                                                     const float* __restrict__ b1,
                                                     const short* __restrict__ W2hi,
                                                     const short* __restrict__ W2lo,
                                                     const float* __restrict__ b2,
                                                     const int* __restrict__ batch,
                                                     float* __restrict__ out,    // raw h2 [N,128]
                                                     float* __restrict__ stats,  // [256]
                                                     float* __restrict__ gout,   // [G, 384]
                                                     int layer) {
    __shared__ unsigned sbuf[8192];  // 32 KB, aliased across phases
    short* As_hi = (short*)sbuf;           // [64][128] shorts, chunk^row swizzle (16 KB)
    short* As_lo = (short*)(sbuf + 4096);  // (16 KB)
    const int tid = threadIdx.x;
    const int base = blockIdx.x * 64;

    // phase 0: stage A (fp32 -> hi/lo trunc split); 64 rows x 128 cols
    const float4* asrc = (const float4*)in;
#pragma unroll
    for (int it = 0; it < 4; ++it) {
        int c = tid + it * 256;  // 0..1023
        int r = c >> 4, ch = c & 15;
        int row = base + r;
        float4 v0 = make_float4(0.f, 0.f, 0.f, 0.f), v1 = v0;
        if (row < N_NODES) {
            v0 = asrc[(size_t)row * 32 + ch * 2];
            v1 = asrc[(size_t)row * 32 + ch * 2 + 1];
        }
        float f[8] = {v0.x, v0.y, v0.z, v0.w, v1.x, v1.y, v1.z, v1.w};
        short8 hi, lo;
#pragma unroll
        for (int j = 0; j < 8; ++j) {
            short h, l;
            split_trunc(f[j], h, l);
            hi[j] = h;
            lo[j] = l;
        }
        int pos = r * 128 + ((ch ^ (r & 15)) * 8);
        *(short8*)&As_hi[pos] = hi;
        *(short8*)&As_lo[pos] = lo;
    }
    __syncthreads();

    const int wave = tid >> 6;
    const int lane = tid & 63;
    const int wm = wave * 16;  // wave's 16-row strip
    const int l15 = lane & 15;
    const int quad = lane >> 4;

    // phase 1: preload A fragments, then GEMM1
    short8 Ahi[4], Alo[4];
#pragma unroll
    for (int ks = 0; ks < 4; ++ks) {
        int row = wm + l15;
        int pos = row * 128 + (((ks * 4 + quad) ^ l15) * 8);
        Ahi[ks] = *(const short8*)&As_hi[pos];
        Alo[ks] = *(const short8*)&As_lo[pos];
    }
    floatx4 acc[8];
#pragma unroll
    for (int ni = 0; ni < 8; ++ni) acc[ni] = floatx4{0.f, 0.f, 0.f, 0.f};
#pragma unroll
    for (int ks = 0; ks < 4; ++ks) {
#pragma unroll
        for (int ni = 0; ni < 8; ++ni) {
            size_t p = (size_t)(ni * 16 + l15) * DIM + ks * 32 + quad * 8;
            short8 bhi = *(const short8*)&W1hi[p];
            short8 blo = *(const short8*)&W1lo[p];
            acc[ni] = __builtin_amdgcn_mfma_f32_16x16x32_bf16(Ahi[ks], bhi, acc[ni], 0, 0, 0);
            acc[ni] = __builtin_amdgcn_mfma_f32_16x16x32_bf16(Alo[ks], bhi, acc[ni], 0, 0, 0);
            acc[ni] = __builtin_amdgcn_mfma_f32_16x16x32_bf16(Ahi[ks], blo, acc[ni], 0, 0, 0);
        }
    }
    __syncthreads();  // all As reads complete before overwrite

    // phase 2: bias1 + relu, trunc-split, pack (hi<<16|lo) -> LDS u32, 16B-chunk swizzle
#pragma unroll
    for (int ni = 0; ni < 8; ++ni) {
        float bv = b1[ni * 16 + l15];
        int col = ni * 16 + l15;
#pragma unroll
        for (int reg = 0; reg < 4; ++reg) {
            int row = wm + quad * 4 + reg;
            float v = fmaxf(acc[ni][reg] + bv, 0.f);
            union { float f; unsigned u; } x{v};
            union { unsigned u; float f; } hf;
            hf.u = x.u & 0xffff0000u;
            union { float f; unsigned u; } y{v - hf.f};
            unsigned w = hf.u | (y.u >> 16);
            sbuf[row * 128 + ((((col >> 2) ^ (row & 31)) * 4) + (col & 3))] = w;
        }
    }
    __syncthreads();

    // phase 3: GEMM2 from packed h1
    floatx4 acc2[8];
#pragma unroll
    for (int ni = 0; ni < 8; ++ni) acc2[ni] = floatx4{0.f, 0.f, 0.f, 0.f};
#pragma unroll
    for (int ks = 0; ks < 4; ++ks) {
        short8 ahi2, alo2;
        {
            int row = wm + l15;
            int c5 = ks * 8 + quad * 2;
            unsigned w[8];
            *(uint4*)&w[0] = *(const uint4*)&sbuf[row * 128 + ((c5 ^ (row & 31)) * 4)];
            *(uint4*)&w[4] = *(const uint4*)&sbuf[row * 128 + (((c5 + 1) ^ (row & 31)) * 4)];
#pragma unroll
            for (int j = 0; j < 8; ++j) {
                ahi2[j] = (short)(w[j] >> 16);
                alo2[j] = (short)(w[j] & 0xffffu);
            }
        }
#pragma unroll
        for (int ni = 0; ni < 8; ++ni) {
            size_t p = (size_t)(ni * 16 + l15) * DIM + ks * 32 + quad * 8;
            short8 bhi = *(const short8*)&W2hi[p];
            short8 blo = *(const short8*)&W2lo[p];
            acc2[ni] = __builtin_amdgcn_mfma_f32_16x16x32_bf16(ahi2, bhi, acc2[ni], 0, 0, 0);
            acc2[ni] = __builtin_amdgcn_mfma_f32_16x16x32_bf16(alo2, bhi, acc2[ni], 0, 0, 0);
            acc2[ni] = __builtin_amdgcn_mfma_f32_16x16x32_bf16(ahi2, blo, acc2[ni], 0, 0, 0);
        }
    }
    __syncthreads();  // phase-3 sbuf reads done; reuse LDS for pool/stats

    // phase 4: epilogue — h2 store + stats (quad-shfl) + pool (ownership LDS), no LDS atomics
    float* pwave = (float*)sbuf;          // [4 wave][4 quad][3 slot][128 col] = 6144 floats
    float* swsum = (float*)sbuf + 6144;   // [4 wave][128]
    float* swsq = (float*)sbuf + 6656;    // [4 wave][128]

    const int g0 = batch[base];
    int idxr[4];
#pragma unroll
    for (int reg = 0; reg < 4; ++reg) {
        int row = base + wm + quad * 4 + reg;
        idxr[reg] = (row < N_NODES) ? (batch[row] - g0) : -1;
    }

#pragma unroll
    for (int ni = 0; ni < 8; ++ni) {
        int col = ni * 16 + l15;
        float bv = b2[col];
        float s_p = 0.f, q_p = 0.f, p0 = 0.f, p1 = 0.f, p2 = 0.f;
#pragma unroll
        for (int reg = 0; reg < 4; ++reg) {
            int idx = idxr[reg];
            if (idx >= 0) {
                int row = base + wm + quad * 4 + reg;
                float v = fmaxf(acc2[ni][reg] + bv, 0.f);
                out[(size_t)row * DIM + col] = v;
                s_p += v;
                q_p += v * v;
                if (idx == 0) p0 += v;
                else if (idx == 1) p1 += v;
                else if (idx == 2) p2 += v;
                else atomicAdd(&gout[(size_t)(g0 + idx) * OUT_STRIDE + layer * DIM + col], v);
            }
        }
        // quad reduction for stats (lanes with same l15)
        s_p += __shfl_xor(s_p, 16);
        s_p += __shfl_xor(s_p, 32);
        q_p += __shfl_xor(q_p, 16);
        q_p += __shfl_xor(q_p, 32);
        if (quad == 0) {
            swsum[wave * 128 + col] = s_p;
            swsq[wave * 128 + col] = q_p;
        }
        // pool: unique writer per (wave,quad,slot,col)
        int pb = ((wave * 4 + quad) * 3) * 128 + col;
        pwave[pb] = p0;
        pwave[pb + 128] = p1;
        pwave[pb + 256] = p2;
    }
    __syncthreads();

    if (tid < 128) {
        float s = swsum[tid] + swsum[128 + tid] + swsum[256 + tid] + swsum[384 + tid];
        atomicAdd(&stats[tid], s);
    } else {
        int c = tid - 128;
        float q = swsq[c] + swsq[128 + c] + swsq[256 + c] + swsq[384 + c];
        atomicAdd(&stats[128 + c], q);
    }
    for (int i = tid; i < 384; i += 256) {
        int slot = i >> 7, col = i & 127;
        float pv = 0.f;
#pragma unroll
        for (int wq = 0; wq < 16; ++wq) pv += pwave[(wq * 3 + slot) * 128 + col];
        int g = g0 + slot;
        if (pv != 0.f && g < N_GRAPHS)
            atomicAdd(&gout[(size_t)g * OUT_STRIDE + layer * DIM + col], pv);
    }
}

// ------- finalize: out[b, l*128+c] = G_l[c]*rawpool + cnt[b]*OFF_l[c] -------
__global__ __launch_bounds__(384) void finalize_kernel(const float* __restrict__ stats3,
                                                       const float* __restrict__ gammas,
                                                       const float* __restrict__ betas,
                                                       const int* __restrict__ cnt,
                                                       float* __restrict__ out) {
    int b = blockIdx.x;
    int l = threadIdx.x >> 7, c = threadIdx.x & 127;
    const float invn = 1.0f / (float)N_NODES;
    const float* st = stats3 + l * 256;
    float m = st[c] * invn;
    float var = st[128 + c] * invn - m * m;
    float inv = rsqrtf(var + BN_EPS);
    float G = gammas[l * DIM + c] * inv;
    float OFF = betas[l * DIM + c] - m * G;
    size_t o = (size_t)b * OUT_STRIDE + threadIdx.x;
    out[o] = fmaf(G, out[o], (float)cnt[b] * OFF);
}

extern "C" void kernel_launch(void* const* d_in, const int* in_sizes, int n_in,
                              void* d_out, int out_size, void* d_ws, size_t ws_size,
                              hipStream_t stream) {
    const float* x = (const float*)d_in[0];
    const int* ei = (const int*)d_in[1];
    const int* srcp = ei;
    const int* dstp = ei + N_EDGES;
    const int* batch = (const int*)d_in[2];
    const float* W1s = (const float*)d_in[3];
    const float* b1s = (const float*)d_in[4];
    const float* W2s = (const float*)d_in[5];
    const float* b2s = (const float*)d_in[6];
    const float* gammas = (const float*)d_in[7];
    const float* betas = (const float*)d_in[8];
    float* out = (float*)d_out;

    float* ws = (float*)d_ws;
    const size_t NF = (size_t)N_NODES * DIM;  // 6.4M floats
    float* hbuf = ws;                         // fp32 [N,128] raw h2 of current layer
    float* agg = ws + NF;                     // fp32 [N,128]
    short* whi = (short*)(ws + 2 * NF);       // bf16 hi [6][128][128]
    short* wlo = whi + 6 * DIM * DIM;         // bf16 lo [6][128][128] (together 98304 floats)
    float* stats3 = ws + 2 * NF + 98304;      // 3*256 floats
    int* cnt = (int*)(stats3 + 3 * 256);      // 512
    int* deg = cnt + N_GRAPHS;                // 50000
    int* ptr = deg + N_NODES;                 // 50001
    int* cursor = ptr + N_NODES + 1;          // 50000
    int* esrc = cursor + N_NODES;             // 600000
    int* partials = esrc + N_EDGES;           // 64

    hipMemsetAsync(out, 0, (size_t)N_GRAPHS * OUT_STRIDE * sizeof(float), stream);
    hipMemsetAsync(stats3, 0, (3 * 256) * sizeof(float) + (N_GRAPHS + N_NODES) * sizeof(int),
                   stream);

    // CSR build (once; reused by all layers) + per-graph node counts
    degree_count_kernel<<<(N_EDGES + 255) / 256, 256, 0, stream>>>(dstp, batch, deg, cnt);
    scan1_kernel<<<N_CHUNKS, 1024, 0, stream>>>(deg, ptr, partials);
    scan2_kernel<<<1, 64, 0, stream>>>(partials);
    scan3_kernel<<<(N_NODES + 256) / 256, 256, 0, stream>>>(partials, ptr, cursor);
    fill_kernel<<<(N_EDGES + 255) / 256, 256, 0, stream>>>(srcp, dstp, cursor, esrc);
    wconv_kernel<<<(6 * DIM * DIM + 255) / 256, 256, 0, stream>>>(W1s, W2s, whi, wlo);

    const int nblk = (N_NODES + 63) / 64;  // 782
    for (int layer = 0; layer < N_LAYERS; ++layer) {
        const float* hin = (layer == 0) ? x : hbuf;
        const float* stp = (layer == 0) ? nullptr : (stats3 + (layer - 1) * 256);
        const float* gp = gammas + (layer - 1) * DIM;  // unused when stp==null
        const float* bp = betas + (layer - 1) * DIM;
        gather_kernel<<<(N_NODES * 64 + 255) / 256, 256, 0, stream>>>(hin, ptr, esrc, stp, gp, bp,
                                                                      agg);
        mlp_kernel<<<nblk, 256, 0, stream>>>(
            agg, whi + ((size_t)layer << 14), wlo + ((size_t)layer << 14), b1s + layer * DIM,
            whi + ((size_t)(3 + layer) << 14), wlo + ((size_t)(3 + layer) << 14),
            b2s + layer * DIM, batch, hbuf, stats3 + layer * 256, out, layer);
    }
    finalize_kernel<<<N_GRAPHS, 384, 0, stream>>>(stats3, gammas, betas, cnt, out);
}

// Round 8
// 524.197 us; speedup vs baseline: 1.1863x; 1.0479x over previous
//
#include <hip/hip_runtime.h>

#define N_NODES 50000
#define N_EDGES 600000
#define DIM 128
#define N_GRAPHS 512
#define N_LAYERS 3
#define OUT_STRIDE (N_LAYERS * DIM)
#define BN_EPS 1e-5f
#define N_CHUNKS 49  // ceil(50000/1024)

typedef __attribute__((ext_vector_type(8))) short short8;
typedef __attribute__((ext_vector_type(4))) float floatx4;

__device__ inline short f2bf(float f) {
    union { float f; unsigned u; } x{f};
    unsigned r = x.u + 0x7fffu + ((x.u >> 16) & 1u);
    return (short)(r >> 16);
}
__device__ inline float bf2f(short h) {
    union { unsigned u; float f; } x;
    x.u = ((unsigned)(unsigned short)h) << 16;
    return x.f;
}
// exact truncation split: f == bf2f(hi) + bf2f(lo) + O(2^-16 |f|)
__device__ inline void split_trunc(float f, short& hi, short& lo) {
    union { float f; unsigned u; } x{f};
    hi = (short)(x.u >> 16);
    union { unsigned u; float f; } hf;
    hf.u = x.u & 0xffff0000u;
    union { float f; unsigned u; } y{f - hf.f};
    lo = (short)(y.u >> 16);
}

// ---------------- CSR build (+ per-graph node count) ----------------
__global__ __launch_bounds__(256) void degree_count_kernel(const int* __restrict__ dst,
                                                           const int* __restrict__ batch,
                                                           int* __restrict__ deg,
                                                           int* __restrict__ cnt) {
    int i = blockIdx.x * 256 + threadIdx.x;
    if (i < N_EDGES) atomicAdd(&deg[dst[i]], 1);
    if (i < N_NODES) atomicAdd(&cnt[batch[i]], 1);
}

__global__ __launch_bounds__(1024) void scan1_kernel(const int* __restrict__ deg,
                                                     int* __restrict__ ptr,
                                                     int* __restrict__ partials) {
    __shared__ int buf[1024];
    int i = blockIdx.x * 1024 + threadIdx.x;
    int v = (i < N_NODES) ? deg[i] : 0;
    buf[threadIdx.x] = v;
    __syncthreads();
    for (int off = 1; off < 1024; off <<= 1) {
        int t = (threadIdx.x >= (unsigned)off) ? buf[threadIdx.x - off] : 0;
        __syncthreads();
        buf[threadIdx.x] += t;
        __syncthreads();
    }
    if (i < N_NODES) ptr[i] = buf[threadIdx.x] - v;  // chunk-local exclusive
    if (threadIdx.x == 1023) partials[blockIdx.x] = buf[1023];
}

__global__ __launch_bounds__(64) void scan2_kernel(int* __restrict__ partials) {
    if (threadIdx.x == 0) {
        int run = 0;
        for (int i = 0; i < N_CHUNKS; ++i) { int t = partials[i]; partials[i] = run; run += t; }
    }
}

__global__ __launch_bounds__(256) void scan3_kernel(const int* __restrict__ partials,
                                                    int* __restrict__ ptr,
                                                    int* __restrict__ cursor) {
    int i = blockIdx.x * 256 + threadIdx.x;
    if (i < N_NODES) {
        int p = ptr[i] + partials[i >> 10];
        ptr[i] = p;
        cursor[i] = p;
    }
    if (i == N_NODES) ptr[N_NODES] = N_EDGES;
}

__global__ __launch_bounds__(256) void fill_kernel(const int* __restrict__ src,
                                                   const int* __restrict__ dst,
                                                   int* __restrict__ cursor,
                                                   int* __restrict__ esrc) {
    int e = blockIdx.x * 256 + threadIdx.x;
    if (e < N_EDGES) {
        int slot = atomicAdd(&cursor[dst[e]], 1);
        esrc[slot] = src[e];
    }
}

// ---------------- weight convert: W[k][n] -> Wt_hi/lo[mat][n][k] (split bf16) ----------------
__global__ __launch_bounds__(256) void wconv_kernel(const float* __restrict__ W1s,
                                                    const float* __restrict__ W2s,
                                                    short* __restrict__ Whi,
                                                    short* __restrict__ Wlo) {
    int idx = blockIdx.x * 256 + threadIdx.x;
    if (idx >= 6 * DIM * DIM) return;
    int mat = idx >> 14;
    int e = idx & 16383;
    int k = e >> 7, n = e & 127;
    const float* W = (mat < 3) ? (W1s + (size_t)mat * DIM * DIM)
                               : (W2s + (size_t)(mat - 3) * DIM * DIM);
    float w = W[e];
    short hi = f2bf(w);
    short lo = f2bf(w - bf2f(hi));
    size_t o = ((size_t)mat << 14) + n * DIM + k;
    Whi[o] = hi;
    Wlo[o] = lo;
}

// ---- gather + inline prev-layer BN affine: agg[n] = G*(h2[n]+sum h2[j]) + (deg+1)*OFF ----
// 32 lanes per node, float4 per lane: 2 nodes/wave, 8 independent 16B loads in flight each.
__global__ __launch_bounds__(256) void gather_kernel(const float* __restrict__ hin,
                                                     const int* __restrict__ ptr,
                                                     const int* __restrict__ esrc,
                                                     const float* __restrict__ stats,  // null=>id
                                                     const float* __restrict__ gamma,
                                                     const float* __restrict__ beta,
                                                     float* __restrict__ agg) {
    int node = (blockIdx.x * 256 + threadIdx.x) >> 5;
    int lane = threadIdx.x & 31;
    if (node >= N_NODES) return;
    floatx4 G = {1.f, 1.f, 1.f, 1.f}, O = {0.f, 0.f, 0.f, 0.f};
    if (stats) {
        const float invn = 1.0f / (float)N_NODES;
        floatx4 s0 = ((const floatx4*)stats)[lane];        // sum
        floatx4 s1 = ((const floatx4*)stats)[32 + lane];   // sumsq
        floatx4 gm = ((const floatx4*)gamma)[lane];
        floatx4 bt = ((const floatx4*)beta)[lane];
        floatx4 m = s0 * invn;
        floatx4 var = s1 * invn - m * m;
        floatx4 inv;
        inv.x = rsqrtf(var.x + BN_EPS);
        inv.y = rsqrtf(var.y + BN_EPS);
        inv.z = rsqrtf(var.z + BN_EPS);
        inv.w = rsqrtf(var.w + BN_EPS);
        G = gm * inv;
        O = bt - m * G;
    }
    const floatx4* h4p = (const floatx4*)hin;
    floatx4 acc = h4p[(size_t)node * 32 + lane];  // self term (eps=0)
    int b = ptr[node], e = ptr[node + 1];
    int j = b;
    for (; j + 8 <= e; j += 8) {
        int s0 = esrc[j], s1 = esrc[j + 1], s2 = esrc[j + 2], s3 = esrc[j + 3];
        int s4 = esrc[j + 4], s5 = esrc[j + 5], s6 = esrc[j + 6], s7 = esrc[j + 7];
        floatx4 v0 = h4p[(size_t)s0 * 32 + lane];
        floatx4 v1 = h4p[(size_t)s1 * 32 + lane];
        floatx4 v2 = h4p[(size_t)s2 * 32 + lane];
        floatx4 v3 = h4p[(size_t)s3 * 32 + lane];
        floatx4 v4 = h4p[(size_t)s4 * 32 + lane];
        floatx4 v5 = h4p[(size_t)s5 * 32 + lane];
        floatx4 v6 = h4p[(size_t)s6 * 32 + lane];
        floatx4 v7 = h4p[(size_t)s7 * 32 + lane];
        acc += ((v0 + v1) + (v2 + v3)) + ((v4 + v5) + (v6 + v7));
    }
    if (j + 4 <= e) {
        int s0 = esrc[j], s1 = esrc[j + 1], s2 = esrc[j + 2], s3 = esrc[j + 3];
        floatx4 v0 = h4p[(size_t)s0 * 32 + lane];
        floatx4 v1 = h4p[(size_t)s1 * 32 + lane];
        floatx4 v2 = h4p[(size_t)s2 * 32 + lane];
        floatx4 v3 = h4p[(size_t)s3 * 32 + lane];
        acc += (v0 + v1) + (v2 + v3);
        j += 4;
    }
    for (; j < e; ++j) {
        int s = esrc[j];
        acc += h4p[(size_t)s * 32 + lane];
    }
    float dp1 = (float)(e - b + 1);
    ((floatx4*)agg)[(size_t)node * 32 + lane] = G * acc + dp1 * O;
}

// -------- fused MLP + BN-stats + raw segmented pool: split-bf16 MFMA --------
// 32-row block (16 KB LDS), 4 waves partition COLUMNS: wave = 32 rows x 32 cols (2mi x 2ni).
// Block reads W exactly once (column ownership). 1563 blocks -> ~6 blocks/CU.
// A hi/lo staged in LDS (XOR swizzle); h1 round-trips through same LDS as packed (hi|lo) u32.
__global__ __launch_bounds__(256, 6) void mlp_kernel(const float* __restrict__ in,
                                                     const short* __restrict__ W1hi,
                                                     const short* __restrict__ W1lo,
                                                     const float* __restrict__ b1,
                                                     const short* __restrict__ W2hi,
                                                     const short* __restrict__ W2lo,
                                                     const float* __restrict__ b2,
                                                     const int* __restrict__ batch,
                                                     float* __restrict__ out,    // raw h2 [N,128]
                                                     float* __restrict__ stats,  // [256]
                                                     float* __restrict__ gout,   // [G, 384]
                                                     int layer) {
    __shared__ unsigned sbuf[4096];  // 16 KB, aliased across phases
    short* As_hi = (short*)sbuf;           // [32][128] shorts, chunk^row swizzle (8 KB)
    short* As_lo = (short*)(sbuf + 2048);  // (8 KB)
    const int tid = threadIdx.x;
    const int base = blockIdx.x * 32;

    // phase 0: stage A (fp32 -> hi/lo trunc split); 32 rows x 128 cols
    const float4* asrc = (const float4*)in;
#pragma unroll
    for (int it = 0; it < 2; ++it) {
        int c = tid + it * 256;  // 0..511
        int r = c >> 4, ch = c & 15;
        int row = base + r;
        float4 v0 = make_float4(0.f, 0.f, 0.f, 0.f), v1 = v0;
        if (row < N_NODES) {
            v0 = asrc[(size_t)row * 32 + ch * 2];
            v1 = asrc[(size_t)row * 32 + ch * 2 + 1];
        }
        float f[8] = {v0.x, v0.y, v0.z, v0.w, v1.x, v1.y, v1.z, v1.w};
        short8 hi, lo;
#pragma unroll
        for (int j = 0; j < 8; ++j) {
            short h, l;
            split_trunc(f[j], h, l);
            hi[j] = h;
            lo[j] = l;
        }
        int pos = r * 128 + ((ch ^ (r & 15)) * 8);
        *(short8*)&As_hi[pos] = hi;
        *(short8*)&As_lo[pos] = lo;
    }
    __syncthreads();

    const int wave = tid >> 6;
    const int lane = tid & 63;
    const int l15 = lane & 15;
    const int quad = lane >> 4;
    // wave owns cols [wave*32, wave*32+32): ni tiles {wave*2, wave*2+1}

    // phase 1: GEMM1 (A from LDS, W fragments from global — each ni read by one wave only)
    floatx4 acc[2][2];
#pragma unroll
    for (int mi = 0; mi < 2; ++mi)
#pragma unroll
        for (int nl = 0; nl < 2; ++nl) acc[mi][nl] = floatx4{0.f, 0.f, 0.f, 0.f};
#pragma unroll
    for (int ks = 0; ks < 4; ++ks) {
        short8 ahi[2], alo[2], bhi[2], blo[2];
#pragma unroll
        for (int mi = 0; mi < 2; ++mi) {
            int row = mi * 16 + l15;
            int pos = row * 128 + (((ks * 4 + quad) ^ l15) * 8);
            ahi[mi] = *(const short8*)&As_hi[pos];
            alo[mi] = *(const short8*)&As_lo[pos];
        }
#pragma unroll
        for (int nl = 0; nl < 2; ++nl) {
            size_t p = (size_t)((wave * 2 + nl) * 16 + l15) * DIM + ks * 32 + quad * 8;
            bhi[nl] = *(const short8*)&W1hi[p];
            blo[nl] = *(const short8*)&W1lo[p];
        }
#pragma unroll
        for (int mi = 0; mi < 2; ++mi)
#pragma unroll
            for (int nl = 0; nl < 2; ++nl) {
                acc[mi][nl] = __builtin_amdgcn_mfma_f32_16x16x32_bf16(ahi[mi], bhi[nl], acc[mi][nl], 0, 0, 0);
                acc[mi][nl] = __builtin_amdgcn_mfma_f32_16x16x32_bf16(alo[mi], bhi[nl], acc[mi][nl], 0, 0, 0);
                acc[mi][nl] = __builtin_amdgcn_mfma_f32_16x16x32_bf16(ahi[mi], blo[nl], acc[mi][nl], 0, 0, 0);
            }
    }
    __syncthreads();  // all As reads complete before overwrite

    // phase 2: bias1 + relu, trunc-split, pack (hi<<16|lo) -> LDS u32, 16B-chunk swizzle
#pragma unroll
    for (int mi = 0; mi < 2; ++mi)
#pragma unroll
        for (int nl = 0; nl < 2; ++nl) {
            int col = (wave * 2 + nl) * 16 + l15;
            float bv = b1[col];
#pragma unroll
            for (int reg = 0; reg < 4; ++reg) {
                int row = mi * 16 + quad * 4 + reg;
                float v = fmaxf(acc[mi][nl][reg] + bv, 0.f);
                union { float f; unsigned u; } x{v};
                union { unsigned u; float f; } hf;
                hf.u = x.u & 0xffff0000u;
                union { float f; unsigned u; } y{v - hf.f};
                unsigned w = hf.u | (y.u >> 16);
                sbuf[row * 128 + ((((col >> 2) ^ (row & 31)) * 4) + (col & 3))] = w;
            }
        }
    __syncthreads();

    // phase 3: GEMM2 from packed h1
    floatx4 acc2[2][2];
#pragma unroll
    for (int mi = 0; mi < 2; ++mi)
#pragma unroll
        for (int nl = 0; nl < 2; ++nl) acc2[mi][nl] = floatx4{0.f, 0.f, 0.f, 0.f};
#pragma unroll
    for (int ks = 0; ks < 4; ++ks) {
        short8 ahi2[2], alo2[2], bhi[2], blo[2];
#pragma unroll
        for (int mi = 0; mi < 2; ++mi) {
            int row = mi * 16 + l15;
            int c5 = ks * 8 + quad * 2;
            unsigned w[8];
            *(uint4*)&w[0] = *(const uint4*)&sbuf[row * 128 + ((c5 ^ (row & 31)) * 4)];
            *(uint4*)&w[4] = *(const uint4*)&sbuf[row * 128 + (((c5 + 1) ^ (row & 31)) * 4)];
#pragma unroll
            for (int j = 0; j < 8; ++j) {
                ahi2[mi][j] = (short)(w[j] >> 16);
                alo2[mi][j] = (short)(w[j] & 0xffffu);
            }
        }
#pragma unroll
        for (int nl = 0; nl < 2; ++nl) {
            size_t p = (size_t)((wave * 2 + nl) * 16 + l15) * DIM + ks * 32 + quad * 8;
            bhi[nl] = *(const short8*)&W2hi[p];
            blo[nl] = *(const short8*)&W2lo[p];
        }
#pragma unroll
        for (int mi = 0; mi < 2; ++mi)
#pragma unroll
            for (int nl = 0; nl < 2; ++nl) {
                acc2[mi][nl] = __builtin_amdgcn_mfma_f32_16x16x32_bf16(ahi2[mi], bhi[nl], acc2[mi][nl], 0, 0, 0);
                acc2[mi][nl] = __builtin_amdgcn_mfma_f32_16x16x32_bf16(alo2[mi], bhi[nl], acc2[mi][nl], 0, 0, 0);
                acc2[mi][nl] = __builtin_amdgcn_mfma_f32_16x16x32_bf16(ahi2[mi], blo[nl], acc2[mi][nl], 0, 0, 0);
            }
    }
    __syncthreads();  // phase-3 sbuf reads done; reuse LDS for pool/stats

    // phase 4: epilogue — h2 store + stats + pool. Each col owned by ONE wave -> unique-writer LDS.
    float* pool_s = (float*)sbuf;        // [3 slot][128 col]
    float* ssum = (float*)sbuf + 384;    // [128]
    float* ssq = (float*)sbuf + 512;     // [128]

    const int g0 = batch[base];
    int idxr[2][4];
#pragma unroll
    for (int mi = 0; mi < 2; ++mi)
#pragma unroll
        for (int reg = 0; reg < 4; ++reg) {
            int row = base + mi * 16 + quad * 4 + reg;
            idxr[mi][reg] = (row < N_NODES) ? (batch[row] - g0) : -1;
        }

#pragma unroll
    for (int nl = 0; nl < 2; ++nl) {
        int col = (wave * 2 + nl) * 16 + l15;
        float bv = b2[col];
        float s_p = 0.f, q_p = 0.f, p0 = 0.f, p1 = 0.f, p2 = 0.f;
#pragma unroll
        for (int mi = 0; mi < 2; ++mi)
#pragma unroll
            for (int reg = 0; reg < 4; ++reg) {
                int idx = idxr[mi][reg];
                if (idx >= 0) {
                    int row = base + mi * 16 + quad * 4 + reg;
                    float v = fmaxf(acc2[mi][nl][reg] + bv, 0.f);
                    out[(size_t)row * DIM + col] = v;
                    s_p += v;
                    q_p += v * v;
                    if (idx == 0) p0 += v;
                    else if (idx == 1) p1 += v;
                    else if (idx == 2) p2 += v;
                    else atomicAdd(&gout[(size_t)(g0 + idx) * OUT_STRIDE + layer * DIM + col], v);
                }
            }
        // quad reduction (lanes sharing l15): full 32-row column totals
        s_p += __shfl_xor(s_p, 16);
        s_p += __shfl_xor(s_p, 32);
        q_p += __shfl_xor(q_p, 16);
        q_p += __shfl_xor(q_p, 32);
        p0 += __shfl_xor(p0, 16);
        p0 += __shfl_xor(p0, 32);
        p1 += __shfl_xor(p1, 16);
        p1 += __shfl_xor(p1, 32);
        p2 += __shfl_xor(p2, 16);
        p2 += __shfl_xor(p2, 32);
        if (quad == 0) {  // unique writer per col
            ssum[col] = s_p;
            ssq[col] = q_p;
            pool_s[col] = p0;
            pool_s[128 + col] = p1;
            pool_s[256 + col] = p2;
        }
    }
    __syncthreads();

    if (tid < 128)
        atomicAdd(&stats[tid], ssum[tid]);
    else
        atomicAdd(&stats[tid], ssq[tid - 128]);
    for (int i = tid; i < 384; i += 256) {
        int slot = i >> 7, col = i & 127;
        float pv = pool_s[slot * 128 + col];
        int g = g0 + slot;
        if (pv != 0.f && g < N_GRAPHS)
            atomicAdd(&gout[(size_t)g * OUT_STRIDE + layer * DIM + col], pv);
    }
}

// ------- finalize: out[b, l*128+c] = G_l[c]*rawpool + cnt[b]*OFF_l[c] -------
__global__ __launch_bounds__(384) void finalize_kernel(const float* __restrict__ stats3,
                                                       const float* __restrict__ gammas,
                                                       const float* __restrict__ betas,
                                                       const int* __restrict__ cnt,
                                                       float* __restrict__ out) {
    int b = blockIdx.x;
    int l = threadIdx.x >> 7, c = threadIdx.x & 127;
    const float invn = 1.0f / (float)N_NODES;
    const float* st = stats3 + l * 256;
    float m = st[c] * invn;
    float var = st[128 + c] * invn - m * m;
    float inv = rsqrtf(var + BN_EPS);
    float G = gammas[l * DIM + c] * inv;
    float OFF = betas[l * DIM + c] - m * G;
    size_t o = (size_t)b * OUT_STRIDE + threadIdx.x;
    out[o] = fmaf(G, out[o], (float)cnt[b] * OFF);
}

extern "C" void kernel_launch(void* const* d_in, const int* in_sizes, int n_in,
                              void* d_out, int out_size, void* d_ws, size_t ws_size,
                              hipStream_t stream) {
    const float* x = (const float*)d_in[0];
    const int* ei = (const int*)d_in[1];
    const int* srcp = ei;
    const int* dstp = ei + N_EDGES;
    const int* batch = (const int*)d_in[2];
    const float* W1s = (const float*)d_in[3];
    const float* b1s = (const float*)d_in[4];
    const float* W2s = (const float*)d_in[5];
    const float* b2s = (const float*)d_in[6];
    const float* gammas = (const float*)d_in[7];
    const float* betas = (const float*)d_in[8];
    float* out = (float*)d_out;

    float* ws = (float*)d_ws;
    const size_t NF = (size_t)N_NODES * DIM;  // 6.4M floats
    float* hbuf = ws;                         // fp32 [N,128] raw h2 of current layer
    float* agg = ws + NF;                     // fp32 [N,128]
    short* whi = (short*)(ws + 2 * NF);       // bf16 hi [6][128][128]
    short* wlo = whi + 6 * DIM * DIM;         // bf16 lo [6][128][128] (together 98304 floats)
    float* stats3 = ws + 2 * NF + 98304;      // 3*256 floats
    int* cnt = (int*)(stats3 + 3 * 256);      // 512
    int* deg = cnt + N_GRAPHS;                // 50000
    int* ptr = deg + N_NODES;                 // 50001
    int* cursor = ptr + N_NODES + 1;          // 50000
    int* esrc = cursor + N_NODES;             // 600000
    int* partials = esrc + N_EDGES;           // 64

    hipMemsetAsync(out, 0, (size_t)N_GRAPHS * OUT_STRIDE * sizeof(float), stream);
    hipMemsetAsync(stats3, 0, (3 * 256) * sizeof(float) + (N_GRAPHS + N_NODES) * sizeof(int),
                   stream);

    // CSR build (once; reused by all layers) + per-graph node counts
    degree_count_kernel<<<(N_EDGES + 255) / 256, 256, 0, stream>>>(dstp, batch, deg, cnt);
    scan1_kernel<<<N_CHUNKS, 1024, 0, stream>>>(deg, ptr, partials);
    scan2_kernel<<<1, 64, 0, stream>>>(partials);
    scan3_kernel<<<(N_NODES + 256) / 256, 256, 0, stream>>>(partials, ptr, cursor);
    fill_kernel<<<(N_EDGES + 255) / 256, 256, 0, stream>>>(srcp, dstp, cursor, esrc);
    wconv_kernel<<<(6 * DIM * DIM + 255) / 256, 256, 0, stream>>>(W1s, W2s, whi, wlo);

    const int nblk = (N_NODES + 31) / 32;  // 1563
    for (int layer = 0; layer < N_LAYERS; ++layer) {
        const float* hin = (layer == 0) ? x : hbuf;
        const float* stp = (layer == 0) ? nullptr : (stats3 + (layer - 1) * 256);
        const float* gp = gammas + (layer - 1) * DIM;  // unused when stp==null
        const float* bp = betas + (layer - 1) * DIM;
        gather_kernel<<<(N_NODES * 32 + 255) / 256, 256, 0, stream>>>(hin, ptr, esrc, stp, gp, bp,
                                                                      agg);
        mlp_kernel<<<nblk, 256, 0, stream>>>(
            agg, whi + ((size_t)layer << 14), wlo + ((size_t)layer << 14), b1s + layer * DIM,
            whi + ((size_t)(3 + layer) << 14), wlo + ((size_t)(3 + layer) << 14),
            b2s + layer * DIM, batch, hbuf, stats3 + layer * 256, out, layer);
    }
    finalize_kernel<<<N_GRAPHS, 384, 0, stream>>>(stats3, gammas, betas, cnt, out);
}

// Round 9
// 480.288 us; speedup vs baseline: 1.2948x; 1.0914x over previous
//
#include <hip/hip_runtime.h>

#define N_NODES 50000
#define N_EDGES 600000
#define DIM 128
#define N_GRAPHS 512
#define N_LAYERS 3
#define OUT_STRIDE (N_LAYERS * DIM)
#define BN_EPS 1e-5f
#define N_CHUNKS 49  // ceil(50000/1024)

typedef __attribute__((ext_vector_type(8))) short short8;
typedef __attribute__((ext_vector_type(4))) float floatx4;

__device__ inline short f2bf(float f) {
    union { float f; unsigned u; } x{f};
    unsigned r = x.u + 0x7fffu + ((x.u >> 16) & 1u);
    return (short)(r >> 16);
}
__device__ inline float bf2f(short h) {
    union { unsigned u; float f; } x;
    x.u = ((unsigned)(unsigned short)h) << 16;
    return x.f;
}
// exact truncation split: f == bf2f(hi) + bf2f(lo) + O(2^-16 |f|)
__device__ inline void split_trunc(float f, short& hi, short& lo) {
    union { float f; unsigned u; } x{f};
    hi = (short)(x.u >> 16);
    union { unsigned u; float f; } hf;
    hf.u = x.u & 0xffff0000u;
    union { float f; unsigned u; } y{f - hf.f};
    lo = (short)(y.u >> 16);
}

// ---------------- CSR build (+ per-graph node count) ----------------
__global__ __launch_bounds__(256) void degree_count_kernel(const int* __restrict__ dst,
                                                           const int* __restrict__ batch,
                                                           int* __restrict__ deg,
                                                           int* __restrict__ cnt) {
    int i = blockIdx.x * 256 + threadIdx.x;
    if (i < N_EDGES) atomicAdd(&deg[dst[i]], 1);
    if (i < N_NODES) atomicAdd(&cnt[batch[i]], 1);
}

__global__ __launch_bounds__(1024) void scan1_kernel(const int* __restrict__ deg,
                                                     int* __restrict__ ptr,
                                                     int* __restrict__ partials) {
    __shared__ int buf[1024];
    int i = blockIdx.x * 1024 + threadIdx.x;
    int v = (i < N_NODES) ? deg[i] : 0;
    buf[threadIdx.x] = v;
    __syncthreads();
    for (int off = 1; off < 1024; off <<= 1) {
        int t = (threadIdx.x >= (unsigned)off) ? buf[threadIdx.x - off] : 0;
        __syncthreads();
        buf[threadIdx.x] += t;
        __syncthreads();
    }
    if (i < N_NODES) ptr[i] = buf[threadIdx.x] - v;  // chunk-local exclusive
    if (threadIdx.x == 1023) partials[blockIdx.x] = buf[1023];
}

__global__ __launch_bounds__(64) void scan2_kernel(int* __restrict__ partials) {
    if (threadIdx.x == 0) {
        int run = 0;
        for (int i = 0; i < N_CHUNKS; ++i) { int t = partials[i]; partials[i] = run; run += t; }
    }
}

__global__ __launch_bounds__(256) void scan3_kernel(const int* __restrict__ partials,
                                                    int* __restrict__ ptr,
                                                    int* __restrict__ cursor) {
    int i = blockIdx.x * 256 + threadIdx.x;
    if (i < N_NODES) {
        int p = ptr[i] + partials[i >> 10];
        ptr[i] = p;
        cursor[i] = p;
    }
    if (i == N_NODES) ptr[N_NODES] = N_EDGES;
}

__global__ __launch_bounds__(256) void fill_kernel(const int* __restrict__ src,
                                                   const int* __restrict__ dst,
                                                   int* __restrict__ cursor,
                                                   int* __restrict__ esrc) {
    int e = blockIdx.x * 256 + threadIdx.x;
    if (e < N_EDGES) {
        int slot = atomicAdd(&cursor[dst[e]], 1);
        esrc[slot] = src[e];
    }
}

// ---------------- weight convert: W[k][n] -> Wt_hi/lo[mat][n][k] (split bf16) ----------------
__global__ __launch_bounds__(256) void wconv_kernel(const float* __restrict__ W1s,
                                                    const float* __restrict__ W2s,
                                                    short* __restrict__ Whi,
                                                    short* __restrict__ Wlo) {
    int idx = blockIdx.x * 256 + threadIdx.x;
    if (idx >= 6 * DIM * DIM) return;
    int mat = idx >> 14;
    int e = idx & 16383;
    int k = e >> 7, n = e & 127;
    const float* W = (mat < 3) ? (W1s + (size_t)mat * DIM * DIM)
                               : (W2s + (size_t)(mat - 3) * DIM * DIM);
    float w = W[e];
    short hi = f2bf(w);
    short lo = f2bf(w - bf2f(hi));
    size_t o = ((size_t)mat << 14) + n * DIM + k;
    Whi[o] = hi;
    Wlo[o] = lo;
}

// ======== fused layer: gather(+prev BN affine) -> GEMM1 -> GEMM2 -> stats+pool ========
// 32-row block (16 KB LDS), 256 threads.
// Gather: half-wave (32 lanes x float4) per node, 4 nodes per half-wave, unroll-8 MLP;
//         result split hi/lo and written straight into the LDS A-tile (XOR swizzle).
// GEMMs: 4 waves partition columns (wave = 32 rows x 32 cols, 2mi x 2nl tiles); W read once/block.
// Epilogue: unique-writer LDS stats/pool, one global atomic per col per block.
__global__ __launch_bounds__(256, 6) void fused_layer_kernel(
    const float* __restrict__ hin,     // prev raw h2 (or x) [N,128]
    const int* __restrict__ ptr,
    const int* __restrict__ esrc,
    const float* __restrict__ pstats,  // prev-layer stats [256] or null (identity)
    const float* __restrict__ pgamma,
    const float* __restrict__ pbeta,
    const short* __restrict__ W1hi, const short* __restrict__ W1lo,
    const float* __restrict__ b1,
    const short* __restrict__ W2hi, const short* __restrict__ W2lo,
    const float* __restrict__ b2,
    const int* __restrict__ batch,
    float* __restrict__ out,    // raw h2 [N,128]
    float* __restrict__ stats,  // this layer's [256]
    float* __restrict__ gout,   // [G, 384]
    int layer) {
    __shared__ unsigned sbuf[4096];  // 16 KB, aliased across phases
    short* As_hi = (short*)sbuf;           // [32][128] shorts, chunk^row swizzle (8 KB)
    short* As_lo = (short*)(sbuf + 2048);  // (8 KB)
    const int tid = threadIdx.x;
    const int base = blockIdx.x * 32;

    // ---- phase G: gather + affine + split -> LDS A-tile ----
    {
        const int hw = tid >> 5;   // half-wave 0..7
        const int l32 = tid & 31;  // lane within half-wave; owns k in [4*l32, 4*l32+4)
        floatx4 G4 = {1.f, 1.f, 1.f, 1.f}, O4 = {0.f, 0.f, 0.f, 0.f};
        if (pstats) {
            const float invn = 1.0f / (float)N_NODES;
            floatx4 s0 = ((const floatx4*)pstats)[l32];
            floatx4 s1 = ((const floatx4*)pstats)[32 + l32];
            floatx4 gm = ((const floatx4*)pgamma)[l32];
            floatx4 bt = ((const floatx4*)pbeta)[l32];
            floatx4 m = s0 * invn;
            floatx4 var = s1 * invn - m * m;
            floatx4 inv;
            inv.x = rsqrtf(var.x + BN_EPS);
            inv.y = rsqrtf(var.y + BN_EPS);
            inv.z = rsqrtf(var.z + BN_EPS);
            inv.w = rsqrtf(var.w + BN_EPS);
            G4 = gm * inv;
            O4 = bt - m * G4;
        }
        const floatx4* h4p = (const floatx4*)hin;
#pragma unroll
        for (int i = 0; i < 4; ++i) {
            int r = hw * 4 + i;
            int node = base + r;
            floatx4 acc = {0.f, 0.f, 0.f, 0.f};
            if (node < N_NODES) {
                acc = h4p[(size_t)node * 32 + l32];  // self (eps=0)
                int b = ptr[node], e = ptr[node + 1];
                int j = b;
                for (; j + 8 <= e; j += 8) {
                    int s0 = esrc[j], s1 = esrc[j + 1], s2 = esrc[j + 2], s3 = esrc[j + 3];
                    int s4 = esrc[j + 4], s5 = esrc[j + 5], s6 = esrc[j + 6], s7 = esrc[j + 7];
                    floatx4 v0 = h4p[(size_t)s0 * 32 + l32];
                    floatx4 v1 = h4p[(size_t)s1 * 32 + l32];
                    floatx4 v2 = h4p[(size_t)s2 * 32 + l32];
                    floatx4 v3 = h4p[(size_t)s3 * 32 + l32];
                    floatx4 v4 = h4p[(size_t)s4 * 32 + l32];
                    floatx4 v5 = h4p[(size_t)s5 * 32 + l32];
                    floatx4 v6 = h4p[(size_t)s6 * 32 + l32];
                    floatx4 v7 = h4p[(size_t)s7 * 32 + l32];
                    acc += ((v0 + v1) + (v2 + v3)) + ((v4 + v5) + (v6 + v7));
                }
                if (j + 4 <= e) {
                    int s0 = esrc[j], s1 = esrc[j + 1], s2 = esrc[j + 2], s3 = esrc[j + 3];
                    floatx4 v0 = h4p[(size_t)s0 * 32 + l32];
                    floatx4 v1 = h4p[(size_t)s1 * 32 + l32];
                    floatx4 v2 = h4p[(size_t)s2 * 32 + l32];
                    floatx4 v3 = h4p[(size_t)s3 * 32 + l32];
                    acc += (v0 + v1) + (v2 + v3);
                    j += 4;
                }
                for (; j < e; ++j) acc += h4p[(size_t)esrc[j] * 32 + l32];
                float dp1 = (float)(e - b + 1);
                acc = G4 * acc + dp1 * O4;
            }
            short hi[4], lo[4];
#pragma unroll
            for (int q = 0; q < 4; ++q) split_trunc(acc[q], hi[q], lo[q]);
            unsigned h0 = (unsigned short)hi[0] | ((unsigned)(unsigned short)hi[1] << 16);
            unsigned h1 = (unsigned short)hi[2] | ((unsigned)(unsigned short)hi[3] << 16);
            unsigned l0 = (unsigned short)lo[0] | ((unsigned)(unsigned short)lo[1] << 16);
            unsigned l1 = (unsigned short)lo[2] | ((unsigned)(unsigned short)lo[3] << 16);
            int ch = l32 >> 1, half = l32 & 1;
            int pos = r * 128 + ((ch ^ (r & 15)) * 8) + half * 4;
            *(uint2*)&As_hi[pos] = make_uint2(h0, h1);
            *(uint2*)&As_lo[pos] = make_uint2(l0, l1);
        }
    }
    __syncthreads();

    const int wave = tid >> 6;
    const int lane = tid & 63;
    const int l15 = lane & 15;
    const int quad = lane >> 4;
    // wave owns cols [wave*32, wave*32+32): ni tiles {wave*2, wave*2+1}

    // ---- phase 1: GEMM1 (A from LDS, W fragments from global; each ni read by one wave) ----
    floatx4 acc[2][2];
#pragma unroll
    for (int mi = 0; mi < 2; ++mi)
#pragma unroll
        for (int nl = 0; nl < 2; ++nl) acc[mi][nl] = floatx4{0.f, 0.f, 0.f, 0.f};
#pragma unroll
    for (int ks = 0; ks < 4; ++ks) {
        short8 ahi[2], alo[2], bhi[2], blo[2];
#pragma unroll
        for (int mi = 0; mi < 2; ++mi) {
            int row = mi * 16 + l15;
            int pos = row * 128 + (((ks * 4 + quad) ^ l15) * 8);
            ahi[mi] = *(const short8*)&As_hi[pos];
            alo[mi] = *(const short8*)&As_lo[pos];
        }
#pragma unroll
        for (int nl = 0; nl < 2; ++nl) {
            size_t p = (size_t)((wave * 2 + nl) * 16 + l15) * DIM + ks * 32 + quad * 8;
            bhi[nl] = *(const short8*)&W1hi[p];
            blo[nl] = *(const short8*)&W1lo[p];
        }
#pragma unroll
        for (int mi = 0; mi < 2; ++mi)
#pragma unroll
            for (int nl = 0; nl < 2; ++nl) {
                acc[mi][nl] = __builtin_amdgcn_mfma_f32_16x16x32_bf16(ahi[mi], bhi[nl], acc[mi][nl], 0, 0, 0);
                acc[mi][nl] = __builtin_amdgcn_mfma_f32_16x16x32_bf16(alo[mi], bhi[nl], acc[mi][nl], 0, 0, 0);
                acc[mi][nl] = __builtin_amdgcn_mfma_f32_16x16x32_bf16(ahi[mi], blo[nl], acc[mi][nl], 0, 0, 0);
            }
    }
    __syncthreads();  // all As reads complete before overwrite

    // ---- phase 2: bias1 + relu, trunc-split, pack (hi<<16|lo) -> LDS u32, 16B-chunk swizzle ----
#pragma unroll
    for (int mi = 0; mi < 2; ++mi)
#pragma unroll
        for (int nl = 0; nl < 2; ++nl) {
            int col = (wave * 2 + nl) * 16 + l15;
            float bv = b1[col];
#pragma unroll
            for (int reg = 0; reg < 4; ++reg) {
                int row = mi * 16 + quad * 4 + reg;
                float v = fmaxf(acc[mi][nl][reg] + bv, 0.f);
                union { float f; unsigned u; } x{v};
                union { unsigned u; float f; } hf;
                hf.u = x.u & 0xffff0000u;
                union { float f; unsigned u; } y{v - hf.f};
                unsigned w = hf.u | (y.u >> 16);
                sbuf[row * 128 + ((((col >> 2) ^ (row & 31)) * 4) + (col & 3))] = w;
            }
        }
    __syncthreads();

    // ---- phase 3: GEMM2 from packed h1 ----
    floatx4 acc2[2][2];
#pragma unroll
    for (int mi = 0; mi < 2; ++mi)
#pragma unroll
        for (int nl = 0; nl < 2; ++nl) acc2[mi][nl] = floatx4{0.f, 0.f, 0.f, 0.f};
#pragma unroll
    for (int ks = 0; ks < 4; ++ks) {
        short8 ahi2[2], alo2[2], bhi[2], blo[2];
#pragma unroll
        for (int mi = 0; mi < 2; ++mi) {
            int row = mi * 16 + l15;
            int c5 = ks * 8 + quad * 2;
            unsigned w[8];
            *(uint4*)&w[0] = *(const uint4*)&sbuf[row * 128 + ((c5 ^ (row & 31)) * 4)];
            *(uint4*)&w[4] = *(const uint4*)&sbuf[row * 128 + (((c5 + 1) ^ (row & 31)) * 4)];
#pragma unroll
            for (int j = 0; j < 8; ++j) {
                ahi2[mi][j] = (short)(w[j] >> 16);
                alo2[mi][j] = (short)(w[j] & 0xffffu);
            }
        }
#pragma unroll
        for (int nl = 0; nl < 2; ++nl) {
            size_t p = (size_t)((wave * 2 + nl) * 16 + l15) * DIM + ks * 32 + quad * 8;
            bhi[nl] = *(const short8*)&W2hi[p];
            blo[nl] = *(const short8*)&W2lo[p];
        }
#pragma unroll
        for (int mi = 0; mi < 2; ++mi)
#pragma unroll
            for (int nl = 0; nl < 2; ++nl) {
                acc2[mi][nl] = __builtin_amdgcn_mfma_f32_16x16x32_bf16(ahi2[mi], bhi[nl], acc2[mi][nl], 0, 0, 0);
                acc2[mi][nl] = __builtin_amdgcn_mfma_f32_16x16x32_bf16(alo2[mi], bhi[nl], acc2[mi][nl], 0, 0, 0);
                acc2[mi][nl] = __builtin_amdgcn_mfma_f32_16x16x32_bf16(ahi2[mi], blo[nl], acc2[mi][nl], 0, 0, 0);
            }
    }
    __syncthreads();  // phase-3 sbuf reads done; reuse LDS for pool/stats

    // ---- phase 4: epilogue — h2 store + stats + pool (unique-writer LDS, col owned by one wave) ----
    float* pool_s = (float*)sbuf;      // [3 slot][128 col]
    float* ssum = (float*)sbuf + 384;  // [128]
    float* ssq = (float*)sbuf + 512;   // [128]

    const int g0 = batch[base];
    int idxr[2][4];
#pragma unroll
    for (int mi = 0; mi < 2; ++mi)
#pragma unroll
        for (int reg = 0; reg < 4; ++reg) {
            int row = base + mi * 16 + quad * 4 + reg;
            idxr[mi][reg] = (row < N_NODES) ? (batch[row] - g0) : -1;
        }

#pragma unroll
    for (int nl = 0; nl < 2; ++nl) {
        int col = (wave * 2 + nl) * 16 + l15;
        float bv = b2[col];
        float s_p = 0.f, q_p = 0.f, p0 = 0.f, p1 = 0.f, p2 = 0.f;
#pragma unroll
        for (int mi = 0; mi < 2; ++mi)
#pragma unroll
            for (int reg = 0; reg < 4; ++reg) {
                int idx = idxr[mi][reg];
                if (idx >= 0) {
                    int row = base + mi * 16 + quad * 4 + reg;
                    float v = fmaxf(acc2[mi][nl][reg] + bv, 0.f);
                    out[(size_t)row * DIM + col] = v;
                    s_p += v;
                    q_p += v * v;
                    if (idx == 0) p0 += v;
                    else if (idx == 1) p1 += v;
                    else if (idx == 2) p2 += v;
                    else atomicAdd(&gout[(size_t)(g0 + idx) * OUT_STRIDE + layer * DIM + col], v);
                }
            }
        s_p += __shfl_xor(s_p, 16);
        s_p += __shfl_xor(s_p, 32);
        q_p += __shfl_xor(q_p, 16);
        q_p += __shfl_xor(q_p, 32);
        p0 += __shfl_xor(p0, 16);
        p0 += __shfl_xor(p0, 32);
        p1 += __shfl_xor(p1, 16);
        p1 += __shfl_xor(p1, 32);
        p2 += __shfl_xor(p2, 16);
        p2 += __shfl_xor(p2, 32);
        if (quad == 0) {  // unique writer per col
            ssum[col] = s_p;
            ssq[col] = q_p;
            pool_s[col] = p0;
            pool_s[128 + col] = p1;
            pool_s[256 + col] = p2;
        }
    }
    __syncthreads();

    if (tid < 128)
        atomicAdd(&stats[tid], ssum[tid]);
    else
        atomicAdd(&stats[tid], ssq[tid - 128]);
    for (int i = tid; i < 384; i += 256) {
        int slot = i >> 7, col = i & 127;
        float pv = pool_s[slot * 128 + col];
        int g = g0 + slot;
        if (pv != 0.f && g < N_GRAPHS)
            atomicAdd(&gout[(size_t)g * OUT_STRIDE + layer * DIM + col], pv);
    }
}

// ------- finalize: out[b, l*128+c] = G_l[c]*rawpool + cnt[b]*OFF_l[c] -------
__global__ __launch_bounds__(384) void finalize_kernel(const float* __restrict__ stats3,
                                                       const float* __restrict__ gammas,
                                                       const float* __restrict__ betas,
                                                       const int* __restrict__ cnt,
                                                       float* __restrict__ out) {
    int b = blockIdx.x;
    int l = threadIdx.x >> 7, c = threadIdx.x & 127;
    const float invn = 1.0f / (float)N_NODES;
    const float* st = stats3 + l * 256;
    float m = st[c] * invn;
    float var = st[128 + c] * invn - m * m;
    float inv = rsqrtf(var + BN_EPS);
    float G = gammas[l * DIM + c] * inv;
    float OFF = betas[l * DIM + c] - m * G;
    size_t o = (size_t)b * OUT_STRIDE + threadIdx.x;
    out[o] = fmaf(G, out[o], (float)cnt[b] * OFF);
}

extern "C" void kernel_launch(void* const* d_in, const int* in_sizes, int n_in,
                              void* d_out, int out_size, void* d_ws, size_t ws_size,
                              hipStream_t stream) {
    const float* x = (const float*)d_in[0];
    const int* ei = (const int*)d_in[1];
    const int* srcp = ei;
    const int* dstp = ei + N_EDGES;
    const int* batch = (const int*)d_in[2];
    const float* W1s = (const float*)d_in[3];
    const float* b1s = (const float*)d_in[4];
    const float* W2s = (const float*)d_in[5];
    const float* b2s = (const float*)d_in[6];
    const float* gammas = (const float*)d_in[7];
    const float* betas = (const float*)d_in[8];
    float* out = (float*)d_out;

    float* ws = (float*)d_ws;
    const size_t NF = (size_t)N_NODES * DIM;  // 6.4M floats
    float* hbufA = ws;                        // fp32 [N,128]
    float* hbufB = ws + NF;                   // fp32 [N,128]
    short* whi = (short*)(ws + 2 * NF);       // bf16 hi [6][128][128]
    short* wlo = whi + 6 * DIM * DIM;         // bf16 lo [6][128][128] (together 98304 floats)
    float* stats3 = ws + 2 * NF + 98304;      // 3*256 floats
    int* cnt = (int*)(stats3 + 3 * 256);      // 512
    int* deg = cnt + N_GRAPHS;                // 50000
    int* ptr = deg + N_NODES;                 // 50001
    int* cursor = ptr + N_NODES + 1;          // 50000
    int* esrc = cursor + N_NODES;             // 600000
    int* partials = esrc + N_EDGES;           // 64

    hipMemsetAsync(out, 0, (size_t)N_GRAPHS * OUT_STRIDE * sizeof(float), stream);
    hipMemsetAsync(stats3, 0, (3 * 256) * sizeof(float) + (N_GRAPHS + N_NODES) * sizeof(int),
                   stream);

    // CSR build (once; reused by all layers) + per-graph node counts
    degree_count_kernel<<<(N_EDGES + 255) / 256, 256, 0, stream>>>(dstp, batch, deg, cnt);
    scan1_kernel<<<N_CHUNKS, 1024, 0, stream>>>(deg, ptr, partials);
    scan2_kernel<<<1, 64, 0, stream>>>(partials);
    scan3_kernel<<<(N_NODES + 256) / 256, 256, 0, stream>>>(partials, ptr, cursor);
    fill_kernel<<<(N_EDGES + 255) / 256, 256, 0, stream>>>(srcp, dstp, cursor, esrc);
    wconv_kernel<<<(6 * DIM * DIM + 255) / 256, 256, 0, stream>>>(W1s, W2s, whi, wlo);

    const int nblk = (N_NODES + 31) / 32;  // 1563
    const float* hin = x;
    float* hout = hbufA;
    for (int layer = 0; layer < N_LAYERS; ++layer) {
        const float* stp = (layer == 0) ? nullptr : (stats3 + (layer - 1) * 256);
        const float* gp = gammas + (layer - 1) * DIM;  // unused when stp==null
        const float* bp = betas + (layer - 1) * DIM;
        fused_layer_kernel<<<nblk, 256, 0, stream>>>(
            hin, ptr, esrc, stp, gp, bp,
            whi + ((size_t)layer << 14), wlo + ((size_t)layer << 14), b1s + layer * DIM,
            whi + ((size_t)(3 + layer) << 14), wlo + ((size_t)(3 + layer) << 14),
            b2s + layer * DIM, batch, hout, stats3 + layer * 256, out, layer);
        hin = hout;
        hout = (hout == hbufA) ? hbufB : hbufA;
    }
    finalize_kernel<<<N_GRAPHS, 384, 0, stream>>>(stats3, gammas, betas, cnt, out);
}